// Round 7
// baseline (515.654 us; speedup 1.0000x reference)
//
#include <hip/hip_runtime.h>
#include <stdint.h>

// Problem constants: B=4096, K=128, D=512, V=128000, sparse=1 always.
// out[b,k] = dot(weight[indices[b,k]], inp[b]) + bias[indices[b,k]]
//
// R5: v-sorted pair stream + D-split-4 compute.
//   R3/R4 measured: weight stream (258MB) evicts the 8MB inp table from L3
//   (~200MB refetch); nt loads did NOT protect it. Fix by construction:
//   process D in 4 slices of 128 floats. Per pass, inp slice = 2MB -> resident
//   in ANY cache level vs a 64MB/pass weight stream. Weight still read once
//   total (nt, ascending-v => sequential-ish). Compute is a balanced pair
//   stream: every wave owns exactly 64 sorted pairs (2 pairs/iter, half-wave
//   each), slice metadata preloaded in registers. Partials per pass -> fixup
//   kernel sums + bias + scatter to out.

constexpr int Kc = 128;
constexpr int Dc = 512;
constexpr int Vc = 128000;

typedef float f4 __attribute__((ext_vector_type(4)));

// ---------------------------------------------------------------------------
// Fallback kernel (R0 verified, 448us): one block per sample b.
// ---------------------------------------------------------------------------
__global__ __launch_bounds__(256) void SparseProjection_kernel(
    const float* __restrict__ inp,
    const int*   __restrict__ indices,
    const float* __restrict__ weight,
    const float* __restrict__ bias,
    float*       __restrict__ out)
{
    const int b    = blockIdx.x;
    const int tid  = threadIdx.x;
    const int lane = tid & 63;
    const int wave = tid >> 6;

    const float4* inp_row = (const float4*)(inp + (size_t)b * Dc);
    const float4 a0 = inp_row[lane];
    const float4 a1 = inp_row[64 + lane];

    const int* idx_base  = indices + (size_t)b * Kc;
    float*     out_base  = out     + (size_t)b * Kc;

    #pragma unroll 4
    for (int i = 0; i < 32; ++i) {
        const int k   = wave * 32 + i;
        const int idx = idx_base[k];
        const float4* wrow = (const float4*)(weight + (size_t)idx * Dc);

        const float4 w0 = wrow[lane];
        const float4 w1 = wrow[64 + lane];

        float s = a0.x * w0.x + a0.y * w0.y + a0.z * w0.z + a0.w * w0.w
                + a1.x * w1.x + a1.y * w1.y + a1.z * w1.z + a1.w * w1.w;

        #pragma unroll
        for (int off = 32; off > 0; off >>= 1)
            s += __shfl_xor(s, off, 64);

        if (lane == 0)
            out_base[k] = s + bias[idx];
    }
}

// ---------------------------------------------------------------------------
// Sort pipeline
// ---------------------------------------------------------------------------

// 1) histogram (int4-vectorized reads)
__global__ __launch_bounds__(256) void hist_kernel(
    const int4* __restrict__ idx4, unsigned int* __restrict__ counts, int n4)
{
    int i      = blockIdx.x * blockDim.x + threadIdx.x;
    int stride = gridDim.x * blockDim.x;
    for (; i < n4; i += stride) {
        int4 v = idx4[i];
        atomicAdd(&counts[v.x], 1u);
        atomicAdd(&counts[v.y], 1u);
        atomicAdd(&counts[v.z], 1u);
        atomicAdd(&counts[v.w], 1u);
    }
}

// 2a) per-chunk sums. CHUNK=512, 250 blocks cover Vc=128000.
__global__ __launch_bounds__(256) void scan1_kernel(
    const unsigned int* __restrict__ counts, unsigned int* __restrict__ partials)
{
    __shared__ unsigned int sm[256];
    const int c = blockIdx.x;
    const int t = threadIdx.x;
    unsigned int a = counts[c * 512 + 2 * t] + counts[c * 512 + 2 * t + 1];
    sm[t] = a;
    __syncthreads();
    for (int off = 128; off > 0; off >>= 1) {
        if (t < off) sm[t] += sm[t + off];
        __syncthreads();
    }
    if (t == 0) partials[c] = sm[0];
}

// 2b) exclusive scan of the 250 partials (single block).
__global__ __launch_bounds__(256) void scan2_kernel(
    unsigned int* __restrict__ partials, int nch)
{
    __shared__ unsigned int sm[256];
    const int t = threadIdx.x;
    unsigned int v = (t < nch) ? partials[t] : 0u;
    sm[t] = v;
    __syncthreads();
    for (int off = 1; off < 256; off <<= 1) {
        unsigned int add = (t >= off) ? sm[t - off] : 0u;
        __syncthreads();
        sm[t] += add;
        __syncthreads();
    }
    if (t < nch) partials[t] = sm[t] - v;   // exclusive
}

// 2c) in-chunk exclusive scan + chunk base -> cursor (in place over counts).
__global__ __launch_bounds__(256) void scan3_kernel(
    unsigned int* __restrict__ counts,          // becomes cursor
    const unsigned int* __restrict__ partials)
{
    __shared__ unsigned int sm[256];
    const int c    = blockIdx.x;
    const int t    = threadIdx.x;
    const int base = c * 512;
    unsigned int c0 = counts[base + 2 * t];
    unsigned int c1 = counts[base + 2 * t + 1];
    unsigned int pair = c0 + c1;
    sm[t] = pair;
    __syncthreads();
    for (int off = 1; off < 256; off <<= 1) {
        unsigned int add = (t >= off) ? sm[t - off] : 0u;
        __syncthreads();
        sm[t] += add;
        __syncthreads();
    }
    unsigned int excl = sm[t] - pair + partials[c];
    counts[base + 2 * t]     = excl;
    counts[base + 2 * t + 1] = excl + c0;
}

// 3) scatter pair ids AND their v into sorted order (int4-vectorized reads)
__global__ __launch_bounds__(256) void scatter_kernel(
    const int4* __restrict__ idx4, unsigned int* __restrict__ cursor,
    unsigned int* __restrict__ sorted, unsigned int* __restrict__ sortedv, int n4)
{
    int i      = blockIdx.x * blockDim.x + threadIdx.x;
    int stride = gridDim.x * blockDim.x;
    for (; i < n4; i += stride) {
        int4 v = idx4[i];
        unsigned int base = 4u * (unsigned int)i;
        unsigned int p;
        p = atomicAdd(&cursor[v.x], 1u); sorted[p] = base + 0; sortedv[p] = (unsigned int)v.x;
        p = atomicAdd(&cursor[v.y], 1u); sorted[p] = base + 1; sortedv[p] = (unsigned int)v.y;
        p = atomicAdd(&cursor[v.z], 1u); sorted[p] = base + 2; sortedv[p] = (unsigned int)v.z;
        p = atomicAdd(&cursor[v.w], 1u); sorted[p] = base + 3; sortedv[p] = (unsigned int)v.w;
    }
}

// ---------------------------------------------------------------------------
// 4) compute pass over one 128-float D-slice. Each wave owns 64 sorted pairs:
//    metadata preloaded (1 load/lane), 2 pairs per iter (half-wave each),
//    dot4 + 5-step shfl reduce, partial stored to this pass's buffer.
// ---------------------------------------------------------------------------
__global__ __launch_bounds__(256) void compute_pass_kernel(
    const float* __restrict__ inp,            // [B, D]
    const float* __restrict__ weight,         // [V, D]
    const unsigned int* __restrict__ sorted,  // [n] pair ids (b*K+k)
    const unsigned int* __restrict__ sortedv, // [n] v per slot
    float* __restrict__ out_part,             // [n] this pass's partials
    int dOff)                                 // pass * 128
{
    const int lane = threadIdx.x & 63;
    const int wid  = (blockIdx.x << 2) + (threadIdx.x >> 6);
    const int j0   = wid << 6;                // 64 pairs per wave
    const int l32  = lane & 31;
    const int half = lane >> 5;

    // whole slice's metadata in registers: one dword load per lane
    const unsigned int s_bk = sorted[j0 + lane];
    const unsigned int s_v  = sortedv[j0 + lane];

    float* outp = out_part + j0;

    #pragma unroll 4
    for (int it = 0; it < 32; ++it) {
        const int pslot = 2 * it + half;      // pair slot within slice
        const unsigned int bk = __shfl(s_bk, pslot, 64);
        const unsigned int v  = __shfl(s_v,  pslot, 64);

        // weight slice: read-once stream, ascending v => keep it non-temporal
        const f4 w = __builtin_nontemporal_load(
            (const f4*)(weight + (size_t)v * Dc + dOff) + l32);
        const f4 a = *((const f4*)(inp + (size_t)(bk >> 7) * Dc + dOff) + l32);

        float s = w.x * a.x + w.y * a.y + w.z * a.z + w.w * a.w;

        s += __shfl_xor(s, 16, 64);
        s += __shfl_xor(s,  8, 64);
        s += __shfl_xor(s,  4, 64);
        s += __shfl_xor(s,  2, 64);
        s += __shfl_xor(s,  1, 64);

        if (l32 == 0)
            outp[pslot] = s;                  // lanes 0 & 32: adjacent 4B
    }
}

// 5) fixup: sum the 4 partials, add bias, scatter to out.
__global__ __launch_bounds__(256) void fixup_kernel(
    const unsigned int* __restrict__ sorted,
    const unsigned int* __restrict__ sortedv,
    const float* __restrict__ p0, const float* __restrict__ p1,
    const float* __restrict__ p2, const float* __restrict__ p3,
    const float* __restrict__ bias,
    float* __restrict__ out, int n)
{
    int j = blockIdx.x * blockDim.x + threadIdx.x;
    if (j < n) {
        float s = ((p0[j] + p1[j]) + (p2[j] + p3[j])) + bias[sortedv[j]];
        out[sorted[j]] = s;
    }
}

// ---------------------------------------------------------------------------
extern "C" void kernel_launch(void* const* d_in, const int* in_sizes, int n_in,
                              void* d_out, int out_size, void* d_ws, size_t ws_size,
                              hipStream_t stream) {
    const float* inp     = (const float*)d_in[0];   // [B, 512] f32
    const int*   indices = (const int*)  d_in[1];   // [B, 128] int32
    // d_in[2] = sparse flag (always 1)
    const float* weight  = (const float*)d_in[3];   // [128000, 512] f32
    const float* bias    = (const float*)d_in[4];   // [128000] f32
    float*       out     = (float*)d_out;           // [B, 128] f32

    const int B = in_sizes[0] / Dc;                 // 4096
    const int n = B * Kc;                           // 524288 pairs

    // ws layout (u32): counts[Vc] | partials[256] | sorted[n] | sortedv[n]
    //                  | out_part[4n floats]
    const size_t need_u32 = (size_t)Vc + 256 + (size_t)2 * n + (size_t)4 * n;
    if ((n & 255) != 0 || ws_size < need_u32 * sizeof(unsigned int)) {
        SparseProjection_kernel<<<B, 256, 0, stream>>>(inp, indices, weight, bias, out);
        return;
    }

    unsigned int* ws       = (unsigned int*)d_ws;
    unsigned int* counts   = ws;                         // Vc (becomes cursor)
    unsigned int* partials = ws + Vc;                    // 256
    unsigned int* sorted   = ws + Vc + 256;              // n
    unsigned int* sortedv  = sorted + n;                 // n
    float*        out_part = (float*)(sortedv + n);      // 4n floats

    const int n4 = n / 4;

    hipMemsetAsync(counts, 0, (size_t)Vc * sizeof(unsigned int), stream);

    hist_kernel<<<512, 256, 0, stream>>>((const int4*)indices, counts, n4);
    scan1_kernel<<<Vc / 512, 256, 0, stream>>>(counts, partials);
    scan2_kernel<<<1, 256, 0, stream>>>(partials, Vc / 512);
    scan3_kernel<<<Vc / 512, 256, 0, stream>>>(counts, partials);
    scatter_kernel<<<512, 256, 0, stream>>>((const int4*)indices, counts,
                                            sorted, sortedv, n4);

    const int cgrid = n / 256;                           // 2048 blocks, 64 pairs/wave
    for (int p = 0; p < 4; ++p) {
        compute_pass_kernel<<<cgrid, 256, 0, stream>>>(
            inp, weight, sorted, sortedv, out_part + (size_t)p * n, p * 128);
    }

    fixup_kernel<<<n / 256, 256, 0, stream>>>(sorted, sortedv,
        out_part, out_part + n, out_part + 2 * (size_t)n, out_part + 3 * (size_t)n,
        bias, out, n);
}

// Round 10
// 468.951 us; speedup vs baseline: 1.0996x; 1.0996x over previous
//
#include <hip/hip_runtime.h>
#include <stdint.h>

// Problem constants: B=4096, K=128, D=512, V=128000, sparse=1 always.
// out[b,k] = dot(weight[indices[b,k]], inp[b]) + bias[indices[b,k]]
//
// R8: v-sorted pair stream + V-SPLIT-2 compute.
//   Measured history: R3 (single-pass v-sort): weight stream 258MB >= L3 256MB
//   -> inp (8MB) forcibly evicted, ~210MB refetch, 3.2 TB/s. R7 (D-split-4):
//   512B/2KB strided weight walk -> DRAM activate-bound, ~25% stream BW. Fix:
//   partition ROWS into 2 contiguous v-ranges. Per pass: weight slice 129MB of
//   WHOLE rows (dense sequential, DRAM-friendly) + inp 8MB = 137MB < 256MB L3
//   -> inp resident by capacity. Pairs are partitioned (each processed once,
//   final out written directly) -- no partials/fixup. Weight read once total.

constexpr int Kc = 128;
constexpr int Dc = 512;
constexpr int Vc = 128000;
constexpr int VSPLIT = 2;                    // rows per pass = Vc/VSPLIT

typedef float f4 __attribute__((ext_vector_type(4)));

// ---------------------------------------------------------------------------
// Fallback kernel (R0 verified, 448us): one block per sample b.
// ---------------------------------------------------------------------------
__global__ __launch_bounds__(256) void SparseProjection_kernel(
    const float* __restrict__ inp,
    const int*   __restrict__ indices,
    const float* __restrict__ weight,
    const float* __restrict__ bias,
    float*       __restrict__ out)
{
    const int b    = blockIdx.x;
    const int tid  = threadIdx.x;
    const int lane = tid & 63;
    const int wave = tid >> 6;

    const float4* inp_row = (const float4*)(inp + (size_t)b * Dc);
    const float4 a0 = inp_row[lane];
    const float4 a1 = inp_row[64 + lane];

    const int* idx_base  = indices + (size_t)b * Kc;
    float*     out_base  = out     + (size_t)b * Kc;

    #pragma unroll 4
    for (int i = 0; i < 32; ++i) {
        const int k   = wave * 32 + i;
        const int idx = idx_base[k];
        const float4* wrow = (const float4*)(weight + (size_t)idx * Dc);

        const float4 w0 = wrow[lane];
        const float4 w1 = wrow[64 + lane];

        float s = a0.x * w0.x + a0.y * w0.y + a0.z * w0.z + a0.w * w0.w
                + a1.x * w1.x + a1.y * w1.y + a1.z * w1.z + a1.w * w1.w;

        #pragma unroll
        for (int off = 32; off > 0; off >>= 1)
            s += __shfl_xor(s, off, 64);

        if (lane == 0)
            out_base[k] = s + bias[idx];
    }
}

// ---------------------------------------------------------------------------
// Sort pipeline (counting sort by v)
// ---------------------------------------------------------------------------

// 1) histogram (int4-vectorized reads)
__global__ __launch_bounds__(256) void hist_kernel(
    const int4* __restrict__ idx4, unsigned int* __restrict__ counts, int n4)
{
    int i      = blockIdx.x * blockDim.x + threadIdx.x;
    int stride = gridDim.x * blockDim.x;
    for (; i < n4; i += stride) {
        int4 v = idx4[i];
        atomicAdd(&counts[v.x], 1u);
        atomicAdd(&counts[v.y], 1u);
        atomicAdd(&counts[v.z], 1u);
        atomicAdd(&counts[v.w], 1u);
    }
}

// 2a) per-chunk sums. CHUNK=512, 250 blocks cover Vc=128000.
__global__ __launch_bounds__(256) void scan1_kernel(
    const unsigned int* __restrict__ counts, unsigned int* __restrict__ partials)
{
    __shared__ unsigned int sm[256];
    const int c = blockIdx.x;
    const int t = threadIdx.x;
    unsigned int a = counts[c * 512 + 2 * t] + counts[c * 512 + 2 * t + 1];
    sm[t] = a;
    __syncthreads();
    for (int off = 128; off > 0; off >>= 1) {
        if (t < off) sm[t] += sm[t + off];
        __syncthreads();
    }
    if (t == 0) partials[c] = sm[0];
}

// 2b) exclusive scan of the 250 partials (single block).
__global__ __launch_bounds__(256) void scan2_kernel(
    unsigned int* __restrict__ partials, int nch)
{
    __shared__ unsigned int sm[256];
    const int t = threadIdx.x;
    unsigned int v = (t < nch) ? partials[t] : 0u;
    sm[t] = v;
    __syncthreads();
    for (int off = 1; off < 256; off <<= 1) {
        unsigned int add = (t >= off) ? sm[t - off] : 0u;
        __syncthreads();
        sm[t] += add;
        __syncthreads();
    }
    if (t < nch) partials[t] = sm[t] - v;   // exclusive
}

// 2c) exclusive scan within each chunk + chunk base; writes starts[] and
//     initializes cursor[] (in-place over counts).
__global__ __launch_bounds__(256) void scan3_kernel(
    unsigned int* __restrict__ counts,          // becomes cursor
    const unsigned int* __restrict__ partials,
    unsigned int* __restrict__ starts,
    int n_total)
{
    __shared__ unsigned int sm[256];
    const int c    = blockIdx.x;
    const int t    = threadIdx.x;
    const int base = c * 512;
    unsigned int c0 = counts[base + 2 * t];
    unsigned int c1 = counts[base + 2 * t + 1];
    unsigned int pair = c0 + c1;
    sm[t] = pair;
    __syncthreads();
    for (int off = 1; off < 256; off <<= 1) {
        unsigned int add = (t >= off) ? sm[t - off] : 0u;
        __syncthreads();
        sm[t] += add;
        __syncthreads();
    }
    unsigned int excl = sm[t] - pair + partials[c];
    unsigned int s0 = excl;
    unsigned int s1 = excl + c0;
    starts[base + 2 * t]     = s0;
    starts[base + 2 * t + 1] = s1;
    counts[base + 2 * t]     = s0;   // cursor init
    counts[base + 2 * t + 1] = s1;
    if (c == 0 && t == 0) starts[Vc] = (unsigned int)n_total;
}

// 3) scatter pair ids into v-sorted order (int4-vectorized reads)
__global__ __launch_bounds__(256) void scatter_kernel(
    const int4* __restrict__ idx4, unsigned int* __restrict__ cursor,
    unsigned int* __restrict__ sorted, int n4)
{
    int i      = blockIdx.x * blockDim.x + threadIdx.x;
    int stride = gridDim.x * blockDim.x;
    for (; i < n4; i += stride) {
        int4 v = idx4[i];
        unsigned int base = 4u * (unsigned int)i;
        unsigned int p;
        p = atomicAdd(&cursor[v.x], 1u); sorted[p] = base + 0;
        p = atomicAdd(&cursor[v.y], 1u); sorted[p] = base + 1;
        p = atomicAdd(&cursor[v.z], 1u); sorted[p] = base + 2;
        p = atomicAdd(&cursor[v.w], 1u); sorted[p] = base + 3;
    }
}

// ---------------------------------------------------------------------------
// 4) compute: one wave per weight row v within [rowBase, rowBase + Vc/VSPLIT).
//    Row (2KB) -> registers (plain loads; nt measured useless). 2-wide pair
//    loop for MLP. Per pass the weight slice (129MB) + inp (8MB) fit L3.
// ---------------------------------------------------------------------------
__device__ __forceinline__ float dot8(f4 a0, f4 a1, f4 w0, f4 w1) {
    return a0.x * w0.x + a0.y * w0.y + a0.z * w0.z + a0.w * w0.w
         + a1.x * w1.x + a1.y * w1.y + a1.z * w1.z + a1.w * w1.w;
}

__global__ __launch_bounds__(256) void compute_sorted_kernel(
    const float* __restrict__ inp,            // [B, D]
    const float* __restrict__ weight,         // [V, D]
    const float* __restrict__ bias,           // [V]
    const unsigned int* __restrict__ starts,  // [V+1]
    const unsigned int* __restrict__ sorted,  // [B*K] pair ids b*K+k
    float* __restrict__ out,                  // [B, K]
    int rowBase)                              // pass * (Vc/VSPLIT)
{
    const int lane = threadIdx.x & 63;
    const int wave = threadIdx.x >> 6;
    const int v    = rowBase + blockIdx.x * 4 + wave;

    const unsigned int s = starts[v];
    const unsigned int e = starts[v + 1];
    if (s == e) return;   // untouched row: skip entirely (no weight read)

    const f4* wrow = (const f4*)(weight + (size_t)v * Dc);
    const f4 w0 = wrow[lane];
    const f4 w1 = wrow[64 + lane];
    const float bv = bias[v];

    unsigned int j = s;
    // 2-wide: two independent inp-row gathers in flight per iteration.
    for (; j + 2 <= e; j += 2) {
        const unsigned int bk0 = sorted[j];
        const unsigned int bk1 = sorted[j + 1];
        const f4* ar0 = (const f4*)(inp + (size_t)(bk0 >> 7) * Dc);
        const f4* ar1 = (const f4*)(inp + (size_t)(bk1 >> 7) * Dc);
        const f4 a00 = ar0[lane];
        const f4 a01 = ar0[64 + lane];
        const f4 a10 = ar1[lane];
        const f4 a11 = ar1[64 + lane];

        float s0 = dot8(a00, a01, w0, w1);
        float s1 = dot8(a10, a11, w0, w1);

        #pragma unroll
        for (int off = 32; off > 0; off >>= 1) {
            s0 += __shfl_xor(s0, off, 64);
            s1 += __shfl_xor(s1, off, 64);
        }

        if (lane == 0) {
            out[bk0] = s0 + bv;
            out[bk1] = s1 + bv;
        }
    }
    if (j < e) {
        const unsigned int bk = sorted[j];
        const f4* arow = (const f4*)(inp + (size_t)(bk >> 7) * Dc);
        const f4 a0 = arow[lane];
        const f4 a1 = arow[64 + lane];

        float sd = dot8(a0, a1, w0, w1);

        #pragma unroll
        for (int off = 32; off > 0; off >>= 1)
            sd += __shfl_xor(sd, off, 64);

        if (lane == 0)
            out[bk] = sd + bv;
    }
}

// ---------------------------------------------------------------------------
extern "C" void kernel_launch(void* const* d_in, const int* in_sizes, int n_in,
                              void* d_out, int out_size, void* d_ws, size_t ws_size,
                              hipStream_t stream) {
    const float* inp     = (const float*)d_in[0];   // [B, 512] f32
    const int*   indices = (const int*)  d_in[1];   // [B, 128] int32
    // d_in[2] = sparse flag (always 1)
    const float* weight  = (const float*)d_in[3];   // [128000, 512] f32
    const float* bias    = (const float*)d_in[4];   // [128000] f32
    float*       out     = (float*)d_out;           // [B, 128] f32

    const int B = in_sizes[0] / Dc;                 // 4096
    const int n = B * Kc;                           // 524288 pairs

    // ws layout (u32): counts[Vc] | starts[Vc+1 pad to +64] | sorted[n] | partials[256]
    const size_t need_u32 = (size_t)2 * Vc + 64 + (size_t)n + 256;
    if ((n & 1023) != 0 || ws_size < need_u32 * sizeof(unsigned int)) {
        SparseProjection_kernel<<<B, 256, 0, stream>>>(inp, indices, weight, bias, out);
        return;
    }

    unsigned int* ws       = (unsigned int*)d_ws;
    unsigned int* counts   = ws;                       // Vc (becomes cursor)
    unsigned int* starts   = ws + Vc;                  // Vc+1 (padded to Vc+64)
    unsigned int* sorted   = ws + 2 * Vc + 64;         // n
    unsigned int* partials = sorted + n;               // 256

    const int n4 = n / 4;

    hipMemsetAsync(counts, 0, (size_t)Vc * sizeof(unsigned int), stream);

    hist_kernel<<<512, 256, 0, stream>>>((const int4*)indices, counts, n4);
    scan1_kernel<<<Vc / 512, 256, 0, stream>>>(counts, partials);
    scan2_kernel<<<1, 256, 0, stream>>>(partials, Vc / 512);
    scan3_kernel<<<Vc / 512, 256, 0, stream>>>(counts, partials, starts, n);
    scatter_kernel<<<512, 256, 0, stream>>>((const int4*)indices, counts, sorted, n4);

    // V-split: each pass covers a contiguous v-range whose weight slice
    // (Vc/VSPLIT * 2KB = 129MB) + inp (8MB) fits in the 256MB L3.
    const int rowsPerPass = Vc / VSPLIT;               // 64000
    for (int p = 0; p < VSPLIT; ++p) {
        compute_sorted_kernel<<<rowsPerPass / 4, 256, 0, stream>>>(
            inp, weight, bias, starts, sorted, out, p * rowsPerPass);
    }
}

// Round 11
// 454.172 us; speedup vs baseline: 1.1354x; 1.0325x over previous
//
#include <hip/hip_runtime.h>

// Problem constants: B=4096, K=128, D=512, V=128000, sparse=1 always.
// out[b,k] = dot(weight[indices[b,k]], inp[b]) + bias[indices[b,k]]
//
// R11: drop the sort (measured net-negative: ~55us prep for ~35us compute gain).
// Attack the unsorted kernel's two candidate limits, attributable via counters:
//  1) MLP/latency: half-wave decomposition (8 half-waves x 16 k's per block),
//     idx preloaded via one load + shfl, 4x dwordx4 per lane per row, unroll 4
//     -> ~2x outstanding requests per wave vs R0's structure, 5-step reduce.
//  2) L3 thrash (266MB working set vs 256MB L3, measured 50% hit): process b in
//     TWO sequential phases; per-phase weight working set ~228MB + inp 8MB fits
//     L3 -> expect FETCH 544 -> ~2x232 MB.

constexpr int Kc = 128;
constexpr int Dc = 512;

typedef float f4 __attribute__((ext_vector_type(4)));

__device__ __forceinline__ float dot4(f4 a, f4 w) {
    return a.x * w.x + a.y * w.y + a.z * w.z + a.w * w.w;
}

__global__ __launch_bounds__(256) void SparseProjection_kernel(
    const float* __restrict__ inp,      // [B, D]
    const int*   __restrict__ indices,  // [B, K]
    const float* __restrict__ weight,   // [V, D]
    const float* __restrict__ bias,     // [V]
    float*       __restrict__ out,      // [B, K]
    int bOff)
{
    const int b    = bOff + blockIdx.x;
    const int tid  = threadIdx.x;
    const int lane = tid & 63;          // lane in wave
    const int l32  = lane & 31;         // lane in half-wave
    const int h    = (lane >> 5);       // half within wave (0/1)
    const int hw   = tid >> 5;          // global half-wave id 0..7

    // inp row: each of 32 lanes covers 16 consecutive floats (64B contiguous).
    const f4* ir = (const f4*)(inp + (size_t)b * Dc);
    const f4 a0 = ir[4 * l32 + 0];
    const f4 a1 = ir[4 * l32 + 1];
    const f4 a2 = ir[4 * l32 + 2];
    const f4 a3 = ir[4 * l32 + 3];

    // Preload this half-wave's 16 indices in one coalesced load (dup in hi 16).
    const int* idx_base = indices + (size_t)b * Kc + hw * 16;
    const int  s_idx    = idx_base[lane & 15];

    float* out_base = out + (size_t)b * Kc + hw * 16;

    #pragma unroll 4
    for (int it = 0; it < 16; ++it) {
        // idx for iteration it of this half: wave-lane h*32 + it holds it.
        const int idx = __shfl(s_idx, h * 32 + it, 64);

        const f4* wr = (const f4*)(weight + (size_t)idx * Dc);
        const f4 w0 = wr[4 * l32 + 0];
        const f4 w1 = wr[4 * l32 + 1];
        const f4 w2 = wr[4 * l32 + 2];
        const f4 w3 = wr[4 * l32 + 3];

        float s = dot4(a0, w0) + dot4(a1, w1) + dot4(a2, w2) + dot4(a3, w3);

        // 5-step butterfly within the 32-lane half (xor<32 stays in-half).
        s += __shfl_xor(s, 16, 64);
        s += __shfl_xor(s,  8, 64);
        s += __shfl_xor(s,  4, 64);
        s += __shfl_xor(s,  2, 64);
        s += __shfl_xor(s,  1, 64);

        if (l32 == 0)
            out_base[it] = s + bias[idx];
    }
}

extern "C" void kernel_launch(void* const* d_in, const int* in_sizes, int n_in,
                              void* d_out, int out_size, void* d_ws, size_t ws_size,
                              hipStream_t stream) {
    const float* inp     = (const float*)d_in[0];   // [B, 512] f32
    const int*   indices = (const int*)  d_in[1];   // [B, 128] int32
    // d_in[2] = sparse flag (always 1) -- dense branch is dead code.
    const float* weight  = (const float*)d_in[3];   // [128000, 512] f32
    const float* bias    = (const float*)d_in[4];   // [128000] f32
    float*       out     = (float*)d_out;           // [B, 128] f32

    const int B = in_sizes[0] / Dc;                 // 4096

    if ((B & 1) == 0) {
        // Two sequential b-phases: per-phase weight working set (~228MB) + inp
        // fits the 256MB L3, cutting thrash misses vs one 266MB-working-set pass.
        const int Bh = B / 2;
        SparseProjection_kernel<<<Bh, 256, 0, stream>>>(inp, indices, weight, bias, out, 0);
        SparseProjection_kernel<<<Bh, 256, 0, stream>>>(inp, indices, weight, bias, out, Bh);
    } else {
        SparseProjection_kernel<<<B, 256, 0, stream>>>(inp, indices, weight, bias, out, 0);
    }
}